// Round 12
// baseline (37.539 us; speedup 1.0000x reference)
//
#include <hip/hip_runtime.h>

// Focal loss: out[0]=loss_pos, out[1]=loss_neg, out[2]=count_pos, out[3]=count_neg
// ALPHA=2, FPN_POS_FACTOR=(2,1), FPN_NEG_FACTOR=(2,1), ANCHOR_POS_FACTOR={1,1}
// logit0: [8,2,64,128,128] f32 (16,777,216), logit1: [8,2,32,64,64] f32 (2,097,152)
//
// Final structure (R11 + R12 trim):
//  - main_kernel: block 0 = pos gather (concurrent, writes out[0]/out[2]);
//    blocks 1..4608 = neg term, 4096 floats each, partial to ws (no atomics --
//    R8 showed cross-XCD fence+atomic completion = 178us).
//  - reduce_ws_kernel: 1 wave, reduces 4608 float2 partials -> out[1]/out[3].
//    Launch-latency bound (~2.5us); single-kernel fusion is structurally
//    worse on this chip.
// Memory plateau: ~5.1 TB/s mixed HBM+L3 for this 4-stream read-once pattern;
// load-schedule variants (VGPR 20-48, prefetch/sched_barrier/asm-tie) do not
// move it (R6-R10).

#define LOG2E 1.44269504088896340736f
#define LN2   0.69314718055994530942f

__device__ __forceinline__ float exp2_hw(float x) { return __builtin_amdgcn_exp2f(x); }
__device__ __forceinline__ float log2_hw(float x) { return __builtin_amdgcn_logf(x); }  // v_log_f32 = log2
__device__ __forceinline__ float rcp_hw(float x)  { return __builtin_amdgcn_rcpf(x); }

// w = sigmoid(x)^2*[g==-1]; loss += softplus(x)*w; count += w
__device__ __forceinline__ void neg_elem(float x, float g, float& lsum, float& csum) {
    float z  = fmaxf(x * LOG2E, -43.0f);    // clamp: below this weight < 1e-26
    float t  = exp2_hw(-z);                 // e^{-x}
    float u  = 1.0f + t;
    float r  = rcp_hw(u);                   // sigmoid(x)
    float w  = (g == -1.0f) ? r * r : 0.0f; // prob^2 * negmask
    float sp = LN2 * (z + log2_hw(u));      // softplus(x)
    csum += w;
    lsum += sp * w;
}

__device__ __forceinline__ void neg_quad(float4 x4, float4 g4, float& lsum, float& csum) {
    neg_elem(x4.x, g4.x, lsum, csum);
    neg_elem(x4.y, g4.y, lsum, csum);
    neg_elem(x4.z, g4.z, lsum, csum);
    neg_elem(x4.w, g4.w, lsum, csum);
}

// Block 0: pos gather (writes out[0], out[2] directly -- no ws dependency).
// Blocks 1..nblk: neg work, 1024 float4-quads each; partial to ws[bid-1].
__global__ void __launch_bounds__(256) main_kernel(
        const float4* __restrict__ x0, const float4* __restrict__ g0,
        const float4* __restrict__ x1, const float4* __restrict__ g1,
        int nblk0,
        const float* __restrict__ logit0, const int* __restrict__ coord0,
        const float* __restrict__ logit1, const int* __restrict__ coord1,
        float2* __restrict__ ws, float* __restrict__ out) {
    const int tid  = threadIdx.x;
    const int lane = tid & 63;
    const int wav  = tid >> 6;
    __shared__ float sa[4], sb[4];

    if (blockIdx.x == 0) {
        // ---- positive (gathered) term: 1024 items, 4 per thread ----
        float lp = 0.0f, cp = 0.0f;
        #pragma unroll
        for (int k = 0; k < 4; ++k) {
            const int item  = tid + k * 256;
            const int level = (item >= 512);
            const int jj    = level ? (item - 512) : item;
            const int b     = jj >> 6;  // P = 64
            const int* cptr = (level ? coord1 : coord0) + jj * 4;
            int c0 = cptr[0], c1 = cptr[1], c2 = cptr[2], c3 = cptr[3];
            const bool v = (c0 > -1);
            const float valid = v ? 1.0f : 0.0f;
            if (!v) { c0 = 0; c1 = 0; c2 = 0; c3 = 0; }
            long off; const float* lg; float posf;
            if (!level) {
                off = ((((long)b * 2 + c0) * 64 + c1) * 128 + c2) * 128 + c3;  // [8][2][64][128][128]
                lg = logit0; posf = 2.0f;
            } else {
                off = ((((long)b * 2 + c0) * 32 + c1) * 64 + c2) * 64 + c3;    // [8][2][32][64][64]
                lg = logit1; posf = 1.0f;
            }
            const float x = lg[off];
            // w = (1-sigmoid(x))^2 * valid;  -log_sigmoid(x) = softplus(-x)
            float z  = fmaxf(-x * LOG2E, -43.0f);
            float t  = exp2_hw(-z);
            float u  = 1.0f + t;
            float r  = rcp_hw(u);               // 1 - sigmoid(x)
            float w  = r * r * valid;
            float sp = LN2 * (z + log2_hw(u));  // softplus(-x)
            lp += sp * w * posf;                // ANCHOR_POS_FACTOR = 1
            cp += w;
        }
        #pragma unroll
        for (int off = 32; off > 0; off >>= 1) {
            lp += __shfl_down(lp, off);
            cp += __shfl_down(cp, off);
        }
        if (lane == 0) { sa[wav] = lp; sb[wav] = cp; }
        __syncthreads();
        if (tid == 0) {
            out[0] = sa[0] + sa[1] + sa[2] + sa[3];
            out[2] = sb[0] + sb[1] + sb[2] + sb[3];
        }
        return;
    }

    // ---- negative term ----
    const int bid = blockIdx.x - 1;
    const float4* __restrict__ xp;
    const float4* __restrict__ gp;
    float f;
    int idx;
    if (bid < nblk0) {
        xp = x0; gp = g0; f = 2.0f;
        idx = bid * 1024 + wav * 256 + lane;
    } else {
        xp = x1; gp = g1; f = 1.0f;
        idx = (bid - nblk0) * 1024 + wav * 256 + lane;
    }
    float4 xa = xp[idx      ];
    float4 ga = gp[idx      ];
    float4 xb = xp[idx +  64];
    float4 gb = gp[idx +  64];
    float4 xc = xp[idx + 128];
    float4 gc = gp[idx + 128];
    float4 xd = xp[idx + 192];
    float4 gd = gp[idx + 192];

    float lsum = 0.0f, csum = 0.0f;
    neg_quad(xa, ga, lsum, csum);
    neg_quad(xb, gb, lsum, csum);
    neg_quad(xc, gc, lsum, csum);
    neg_quad(xd, gd, lsum, csum);
    lsum *= f;  // FPN_NEG_FACTOR baked per block

    #pragma unroll
    for (int off = 32; off > 0; off >>= 1) {
        lsum += __shfl_down(lsum, off);
        csum += __shfl_down(csum, off);
    }
    if (lane == 0) { sa[wav] = lsum; sb[wav] = csum; }
    __syncthreads();
    if (tid == 0) {
        ws[bid] = make_float2(sa[0] + sa[1] + sa[2] + sa[3],
                              sb[0] + sb[1] + sb[2] + sb[3]);
    }
}

// One wave: reduce nblk float2 partials -> out[1], out[3]. No LDS, no sync.
// ws read as float4 (two partials per load): 2304 float4s, 36 per lane.
__global__ void __launch_bounds__(64) reduce_ws_kernel(
        const float4* __restrict__ ws4, int nq,
        float* __restrict__ out) {
    const int lane = threadIdx.x;
    float ln = 0.0f, cn = 0.0f;
    for (int i = lane; i < nq; i += 64) {
        float4 v = ws4[i];
        ln += v.x + v.z;
        cn += v.y + v.w;
    }
    #pragma unroll
    for (int off = 32; off > 0; off >>= 1) {
        ln += __shfl_down(ln, off);
        cn += __shfl_down(cn, off);
    }
    if (lane == 0) {
        out[1] = ln;
        out[3] = cn;
    }
}

extern "C" void kernel_launch(void* const* d_in, const int* in_sizes, int n_in,
                              void* d_out, int out_size, void* d_ws, size_t ws_size,
                              hipStream_t stream) {
    const float* logit0 = (const float*)d_in[0];
    const float* logit1 = (const float*)d_in[1];
    const float* gt0    = (const float*)d_in[2];
    const float* gt1    = (const float*)d_in[3];
    const int*   coord0 = (const int*)d_in[4];
    const int*   coord1 = (const int*)d_in[5];
    float* out = (float*)d_out;
    float2* ws = (float2*)d_ws;

    const int n0 = in_sizes[0];  // 16,777,216 = 4096 blocks * 4096 floats
    const int n1 = in_sizes[1];  //  2,097,152 =  512 blocks * 4096 floats
    const int nblk0 = n0 >> 12;
    const int nblk1 = n1 >> 12;
    const int nblk = nblk0 + nblk1;          // 4608 neg blocks

    main_kernel<<<nblk + 1, 256, 0, stream>>>(
        (const float4*)logit0, (const float4*)gt0,
        (const float4*)logit1, (const float4*)gt1, nblk0,
        logit0, coord0, logit1, coord1, ws, out);
    reduce_ws_kernel<<<1, 64, 0, stream>>>(
        (const float4*)ws, nblk / 2, out);
}

// Round 13
// 30.882 us; speedup vs baseline: 1.2156x; 1.2156x over previous
//
#include <hip/hip_runtime.h>

// Focal loss: out[0]=loss_pos, out[1]=loss_neg, out[2]=count_pos, out[3]=count_neg
// ALPHA=2, FPN_POS_FACTOR=(2,1), FPN_NEG_FACTOR=(2,1), ANCHOR_POS_FACTOR={1,1}
// logit0: [8,2,64,128,128] f32 (16,777,216), logit1: [8,2,32,64,64] f32 (2,097,152)
//
// R13 = exact revert to R11 (best: 30.7us). R12's one-wave reduce regressed
// (36 latency-bound loads/lane vs 9) -- reduce kernel needs parallelism too.
// Structure:
//  - main_kernel: block 0 = pos gather (concurrent, writes out[0]/out[2]);
//    blocks 1..4608 = neg term, 4096 floats each, partial to ws (no atomics --
//    R8: cross-XCD fence+atomic completion = 178us).
//  - reduce_ws_kernel: 256 threads, reduces 4608 float2 partials (9 float4/
//    thread) -> out[1]/out[3]. ~2.5us, launch-latency bound.
// Memory plateau: ~5.1 TB/s mixed HBM+L3 for this 4-stream read-once pattern;
// load-schedule variants (VGPR 20-48, prefetch/sched_barrier/asm-tie) do not
// move it (R6-R10).

#define LOG2E 1.44269504088896340736f
#define LN2   0.69314718055994530942f

__device__ __forceinline__ float exp2_hw(float x) { return __builtin_amdgcn_exp2f(x); }
__device__ __forceinline__ float log2_hw(float x) { return __builtin_amdgcn_logf(x); }  // v_log_f32 = log2
__device__ __forceinline__ float rcp_hw(float x)  { return __builtin_amdgcn_rcpf(x); }

// w = sigmoid(x)^2*[g==-1]; loss += softplus(x)*w; count += w
__device__ __forceinline__ void neg_elem(float x, float g, float& lsum, float& csum) {
    float z  = fmaxf(x * LOG2E, -43.0f);    // clamp: below this weight < 1e-26
    float t  = exp2_hw(-z);                 // e^{-x}
    float u  = 1.0f + t;
    float r  = rcp_hw(u);                   // sigmoid(x)
    float w  = (g == -1.0f) ? r * r : 0.0f; // prob^2 * negmask
    float sp = LN2 * (z + log2_hw(u));      // softplus(x)
    csum += w;
    lsum += sp * w;
}

__device__ __forceinline__ void neg_quad(float4 x4, float4 g4, float& lsum, float& csum) {
    neg_elem(x4.x, g4.x, lsum, csum);
    neg_elem(x4.y, g4.y, lsum, csum);
    neg_elem(x4.z, g4.z, lsum, csum);
    neg_elem(x4.w, g4.w, lsum, csum);
}

// Block 0: pos gather (writes out[0], out[2] directly -- no ws dependency).
// Blocks 1..nblk: neg work, 1024 float4-quads each; partial to ws[bid-1].
__global__ void __launch_bounds__(256, 2) main_kernel(
        const float4* __restrict__ x0, const float4* __restrict__ g0,
        const float4* __restrict__ x1, const float4* __restrict__ g1,
        int nblk0,
        const float* __restrict__ logit0, const int* __restrict__ coord0,
        const float* __restrict__ logit1, const int* __restrict__ coord1,
        float2* __restrict__ ws, float* __restrict__ out) {
    const int tid  = threadIdx.x;
    const int lane = tid & 63;
    const int wav  = tid >> 6;
    __shared__ float sa[4], sb[4];

    if (blockIdx.x == 0) {
        // ---- positive (gathered) term: 1024 items, 4 per thread ----
        float lp = 0.0f, cp = 0.0f;
        #pragma unroll
        for (int k = 0; k < 4; ++k) {
            const int item  = tid + k * 256;
            const int level = (item >= 512);
            const int jj    = level ? (item - 512) : item;
            const int b     = jj >> 6;  // P = 64
            const int* cptr = (level ? coord1 : coord0) + jj * 4;
            int c0 = cptr[0], c1 = cptr[1], c2 = cptr[2], c3 = cptr[3];
            const bool v = (c0 > -1);
            const float valid = v ? 1.0f : 0.0f;
            if (!v) { c0 = 0; c1 = 0; c2 = 0; c3 = 0; }
            long off; const float* lg; float posf;
            if (!level) {
                off = ((((long)b * 2 + c0) * 64 + c1) * 128 + c2) * 128 + c3;  // [8][2][64][128][128]
                lg = logit0; posf = 2.0f;
            } else {
                off = ((((long)b * 2 + c0) * 32 + c1) * 64 + c2) * 64 + c3;    // [8][2][32][64][64]
                lg = logit1; posf = 1.0f;
            }
            const float x = lg[off];
            // w = (1-sigmoid(x))^2 * valid;  -log_sigmoid(x) = softplus(-x)
            float z  = fmaxf(-x * LOG2E, -43.0f);
            float t  = exp2_hw(-z);
            float u  = 1.0f + t;
            float r  = rcp_hw(u);               // 1 - sigmoid(x)
            float w  = r * r * valid;
            float sp = LN2 * (z + log2_hw(u));  // softplus(-x)
            lp += sp * w * posf;                // ANCHOR_POS_FACTOR = 1
            cp += w;
        }
        #pragma unroll
        for (int off = 32; off > 0; off >>= 1) {
            lp += __shfl_down(lp, off);
            cp += __shfl_down(cp, off);
        }
        if (lane == 0) { sa[wav] = lp; sb[wav] = cp; }
        __syncthreads();
        if (tid == 0) {
            out[0] = sa[0] + sa[1] + sa[2] + sa[3];
            out[2] = sb[0] + sb[1] + sb[2] + sb[3];
        }
        return;
    }

    // ---- negative term ----
    const int bid = blockIdx.x - 1;
    const float4* __restrict__ xp;
    const float4* __restrict__ gp;
    float f;
    int idx;
    if (bid < nblk0) {
        xp = x0; gp = g0; f = 2.0f;
        idx = bid * 1024 + wav * 256 + lane;
    } else {
        xp = x1; gp = g1; f = 1.0f;
        idx = (bid - nblk0) * 1024 + wav * 256 + lane;
    }
    float4 xa = xp[idx      ];
    float4 ga = gp[idx      ];
    float4 xb = xp[idx +  64];
    float4 gb = gp[idx +  64];
    float4 xc = xp[idx + 128];
    float4 gc = gp[idx + 128];
    float4 xd = xp[idx + 192];
    float4 gd = gp[idx + 192];

    float lsum = 0.0f, csum = 0.0f;
    neg_quad(xa, ga, lsum, csum);
    neg_quad(xb, gb, lsum, csum);
    neg_quad(xc, gc, lsum, csum);
    neg_quad(xd, gd, lsum, csum);
    lsum *= f;  // FPN_NEG_FACTOR baked per block

    #pragma unroll
    for (int off = 32; off > 0; off >>= 1) {
        lsum += __shfl_down(lsum, off);
        csum += __shfl_down(csum, off);
    }
    if (lane == 0) { sa[wav] = lsum; sb[wav] = csum; }
    __syncthreads();
    if (tid == 0) {
        ws[bid] = make_float2(sa[0] + sa[1] + sa[2] + sa[3],
                              sb[0] + sb[1] + sb[2] + sb[3]);
    }
}

// 256 threads, one block: reduce nblk float2 partials -> out[1], out[3].
// ws read as float4 (two partials per load): 2304 float4s, 9 per thread.
__global__ void __launch_bounds__(256) reduce_ws_kernel(
        const float4* __restrict__ ws4, int nq,
        float* __restrict__ out) {
    const int tid = threadIdx.x;
    float ln = 0.0f, cn = 0.0f;
    for (int i = tid; i < nq; i += 256) {
        float4 v = ws4[i];
        ln += v.x + v.z;
        cn += v.y + v.w;
    }
    #pragma unroll
    for (int off = 32; off > 0; off >>= 1) {
        ln += __shfl_down(ln, off);
        cn += __shfl_down(cn, off);
    }
    __shared__ float sl[4], sc[4];
    const int wav = tid >> 6, lane = tid & 63;
    if (lane == 0) { sl[wav] = ln; sc[wav] = cn; }
    __syncthreads();
    if (tid == 0) {
        out[1] = sl[0] + sl[1] + sl[2] + sl[3];
        out[3] = sc[0] + sc[1] + sc[2] + sc[3];
    }
}

extern "C" void kernel_launch(void* const* d_in, const int* in_sizes, int n_in,
                              void* d_out, int out_size, void* d_ws, size_t ws_size,
                              hipStream_t stream) {
    const float* logit0 = (const float*)d_in[0];
    const float* logit1 = (const float*)d_in[1];
    const float* gt0    = (const float*)d_in[2];
    const float* gt1    = (const float*)d_in[3];
    const int*   coord0 = (const int*)d_in[4];
    const int*   coord1 = (const int*)d_in[5];
    float* out = (float*)d_out;
    float2* ws = (float2*)d_ws;

    const int n0 = in_sizes[0];  // 16,777,216 = 4096 blocks * 4096 floats
    const int n1 = in_sizes[1];  //  2,097,152 =  512 blocks * 4096 floats
    const int nblk0 = n0 >> 12;
    const int nblk1 = n1 >> 12;
    const int nblk = nblk0 + nblk1;          // 4608 neg blocks

    main_kernel<<<nblk + 1, 256, 0, stream>>>(
        (const float4*)logit0, (const float4*)gt0,
        (const float4*)logit1, (const float4*)gt1, nblk0,
        logit0, coord0, logit1, coord1, ws, out);
    reduce_ws_kernel<<<1, 256, 0, stream>>>(
        (const float4*)ws, nblk / 2, out);
}